// Round 8
// baseline (489.253 us; speedup 1.0000x reference)
//
#include <hip/hip_runtime.h>

#define T_STEPS 4096
#define BATCH   2048
#define HID     10
#define UB      16   // steps per buffer; outer loop advances 2*UB (ping-pong)

// ---- R7/R8-proven load skeleton ------------------------------------------
__device__ __forceinline__ void issue16(float (&xr)[UB], const float* base) {
#pragma unroll
    for (int u = 0; u < UB; ++u)
        asm volatile("global_load_dword %0, %1, off"
                     : "=v"(xr[u]) : "v"(base + (size_t)u * BATCH) : "memory");
}
#define BIND16(a) "+v"(a[0]),"+v"(a[1]),"+v"(a[2]),"+v"(a[3]),"+v"(a[4]), \
    "+v"(a[5]),"+v"(a[6]),"+v"(a[7]),"+v"(a[8]),"+v"(a[9]),"+v"(a[10]),   \
    "+v"(a[11]),"+v"(a[12]),"+v"(a[13]),"+v"(a[14]),"+v"(a[15])
__device__ __forceinline__ void wait1_bind(float (&xr)[UB]) {
    asm volatile("s_waitcnt vmcnt(1)" : BIND16(xr) :: "memory");
}
__device__ __forceinline__ void wait0_bind(float (&xr)[UB]) {
    asm volatile("s_waitcnt vmcnt(0)" : BIND16(xr) :: "memory");
}

// ---- R16: R15 step UNCHANGED; parallelization changed to 2 waves/SIMD -----
// Occupancy-cadence model (fit R8-R15, R15 quantitatively confirmed):
// wall/step = Sum(rate-cycles): VALU~4, trans~16, ds~8; nops/waits free.
// R15 = ~125 cyc/step vs ~116 floor -> per-wave shaving nearly exhausted.
// R16 tests the LAST structural lever: SIMD sharing. Every prior round ran
// <=1 wave/SIMD. If trans (exp/rcp) drains on a separate pipe and the lone
// wave is limited by its 4-cyc self-issue cadence, TWO co-resident waves
// overlap: A's VALU issues under B's trans and vice versa (up to 1.36x).
// Config: 1 batch per wave on lanes 0..15 (lanes 16-63 early-return; per-wave
// issue stream identical to R15), grid = 2048 waves = 8/CU = 2/SIMD.
// Clean A/B: hot loop byte-identical to R15.
#define STEP_HEAD \
    "v_fma_f32 %[c0], %[wih2], %[x], %[bj2]\n\t"                                   /* 1 */ \
    "v_fmac_f32 %[c0], %[r], %[w0]\n\t"                                            /* 2 plain r, dist3 from rcp */ \
    "v_mul_f32_dpp %[c1], %[r], %[w1] row_ror:1 row_mask:0xf bank_mask:0xf\n\t"    /* 3 DPP r, dist4 */ \
    "v_fmac_f32_dpp %[c0], %[r], %[w2] row_ror:2 row_mask:0xf bank_mask:0xf\n\t"   /* 4 */ \
    "v_fmac_f32_dpp %[c1], %[r], %[w3] row_ror:3 row_mask:0xf bank_mask:0xf\n\t"   /* 5 */ \
    "v_fmac_f32_dpp %[c0], %[r], %[w4] row_ror:4 row_mask:0xf bank_mask:0xf\n\t"   /* 6 */ \
    "v_fmac_f32_dpp %[c1], %[r], %[w5] row_ror:5 row_mask:0xf bank_mask:0xf\n\t"   /* 7 */ \
    "v_fmac_f32_dpp %[c0], %[r], %[w6] row_ror:6 row_mask:0xf bank_mask:0xf\n\t"   /* 8 */ \
    "v_fmac_f32_dpp %[c1], %[r], %[w7] row_ror:7 row_mask:0xf bank_mask:0xf\n\t"   /* 9 */ \
    "v_fmac_f32_dpp %[c0], %[r], %[w8] row_ror:8 row_mask:0xf bank_mask:0xf\n\t"   /* 10 */ \
    "v_fmac_f32_dpp %[c1], %[r], %[w9] row_ror:9 row_mask:0xf bank_mask:0xf\n\t"   /* 11 */ \
    "v_fmac_f32_dpp %[c0], %[r], %[w10] row_ror:10 row_mask:0xf bank_mask:0xf\n\t" /* 12 */ \
    "v_fmac_f32_dpp %[c1], %[r], %[w11] row_ror:11 row_mask:0xf bank_mask:0xf\n\t" /* 13 */ \
    "v_fmac_f32_dpp %[c0], %[r], %[w12] row_ror:12 row_mask:0xf bank_mask:0xf\n\t" /* 14 */ \
    "v_fmac_f32_dpp %[c1], %[r], %[w13] row_ror:13 row_mask:0xf bank_mask:0xf\n\t" /* 15 */ \
    "v_fmac_f32_dpp %[c0], %[r], %[w14] row_ror:14 row_mask:0xf bank_mask:0xf\n\t" /* 16 */ \
    "v_fmac_f32_dpp %[c1], %[r], %[w15] row_ror:15 row_mask:0xf bank_mask:0xf\n\t" /* 17 */ \
    "v_add_f32 %[c0], %[c0], %[c1]\n\t"                                            /* 18 c1 dist1 (R10-proven) */ \
    "v_exp_f32 %[ex], %[c0]\n\t"                                                   /* 19 c0 dist1 (R10-proven) */ \
    "s_nop 0\n\t"                                                                  /* trans-use wait */ \
    "v_add_f32 %[ex], 1.0, %[ex]\n\t"                                              /* 20 */

#define STEP_TAIL \
    "v_rcp_f32 %[r], %[ex]\n\t"                                                    /* 22 ex dist2 (R10-proven) */ \
    "s_nop 0"                                                                      /* trans-use wait */

// pk extraction (slot 21, c0 dist3+nop from slot 18 — R10-proven spacing):
// lane (U-1)&15 <- lane 10's c0 via row_ror:(U+5)&15.
#define PKDPP(N) "v_fmac_f32_dpp %[pk], %[c0], %[m] row_ror:" #N " row_mask:0xf bank_mask:0xf\n\t"
#define PKPLAIN  "v_fmac_f32 %[pk], %[c0], %[m]\n\t"

#define DEF_STEP(SUF, PKLINE_) \
__device__ __forceinline__ void step_##SUF(float& r, float& pk, float x, \
        float wih2, float bj2, float m, const float (&w)[16]) { \
    float c0, c1, ex; \
    asm volatile( STEP_HEAD PKLINE_ STEP_TAIL \
        : [c0]"=&v"(c0), [c1]"=&v"(c1), [ex]"=&v"(ex), \
          [r]"+v"(r), [pk]"+v"(pk) \
        : [x]"v"(x), [wih2]"v"(wih2), [bj2]"v"(bj2), [m]"v"(m), \
          [w0]"v"(w[0]),  [w1]"v"(w[1]),  [w2]"v"(w[2]),  [w3]"v"(w[3]), \
          [w4]"v"(w[4]),  [w5]"v"(w[5]),  [w6]"v"(w[6]),  [w7]"v"(w[7]), \
          [w8]"v"(w[8]),  [w9]"v"(w[9]),  [w10]"v"(w[10]),[w11]"v"(w[11]), \
          [w12]"v"(w[12]),[w13]"v"(w[13]),[w14]"v"(w[14]),[w15]"v"(w[15])); \
}

DEF_STEP(r0,  PKPLAIN)
DEF_STEP(r1,  PKDPP(1))
DEF_STEP(r2,  PKDPP(2))
DEF_STEP(r3,  PKDPP(3))
DEF_STEP(r4,  PKDPP(4))
DEF_STEP(r5,  PKDPP(5))
DEF_STEP(r6,  PKDPP(6))
DEF_STEP(r7,  PKDPP(7))
DEF_STEP(r8,  PKDPP(8))
DEF_STEP(r9,  PKDPP(9))
DEF_STEP(r10, PKDPP(10))
DEF_STEP(r11, PKDPP(11))
DEF_STEP(r12, PKDPP(12))
DEF_STEP(r13, PKDPP(13))
DEF_STEP(r14, PKDPP(14))
DEF_STEP(r15, PKDPP(15))

// Dispatcher: step U extracts out-row t0+U-1 to lane (U-1)&15 via
// ROT=(U+5)&15 (R10/R15-proven). U=0 wraps: mask km[15] -> lane 15 carries
// y_{t0-1} (stored this block; skipped for t0=0). No per-16 finisher.
template<int U>
__device__ __forceinline__ void step_u(float& r, float& pk, float x,
                                       float wih2, float bj2,
                                       const float (&km)[16],
                                       const float (&w)[16]) {
    constexpr int ROT = (U + 5) & 15;
    const float m = km[(U + 15) & 15];
    if constexpr (ROT == 0)       step_r0 (r, pk, x, wih2, bj2, m, w);
    else if constexpr (ROT == 1)  step_r1 (r, pk, x, wih2, bj2, m, w);
    else if constexpr (ROT == 2)  step_r2 (r, pk, x, wih2, bj2, m, w);
    else if constexpr (ROT == 3)  step_r3 (r, pk, x, wih2, bj2, m, w);
    else if constexpr (ROT == 4)  step_r4 (r, pk, x, wih2, bj2, m, w);
    else if constexpr (ROT == 5)  step_r5 (r, pk, x, wih2, bj2, m, w);
    else if constexpr (ROT == 6)  step_r6 (r, pk, x, wih2, bj2, m, w);
    else if constexpr (ROT == 7)  step_r7 (r, pk, x, wih2, bj2, m, w);
    else if constexpr (ROT == 8)  step_r8 (r, pk, x, wih2, bj2, m, w);
    else if constexpr (ROT == 9)  step_r9 (r, pk, x, wih2, bj2, m, w);
    else if constexpr (ROT == 10) step_r10(r, pk, x, wih2, bj2, m, w);
    else if constexpr (ROT == 11) step_r11(r, pk, x, wih2, bj2, m, w);
    else if constexpr (ROT == 12) step_r12(r, pk, x, wih2, bj2, m, w);
    else if constexpr (ROT == 13) step_r13(r, pk, x, wih2, bj2, m, w);
    else if constexpr (ROT == 14) step_r14(r, pk, x, wih2, bj2, m, w);
    else                          step_r15(r, pk, x, wih2, bj2, m, w);
}

template<int U>
__device__ __forceinline__ void run16(float& r, float& pk, const float (&xr)[UB],
                                      float wih2, float bj2,
                                      const float (&km)[16],
                                      const float (&w)[16]) {
    if constexpr (U < UB) {
        step_u<U>(r, pk, xr[U], wih2, bj2, km, w);
        run16<U + 1>(r, pk, xr, wih2, bj2, km, w);
    }
}

// Post-loop finisher (R8-proven): rotational butterfly -> every lane holds
// y_{4095}-C0; keep on lane 0 via mask.
__device__ __forceinline__ void finish_reduce(float r, float& p, float& pk,
                                              float wo2, float m0) {
    asm volatile(
        "v_mul_f32 %[p], %[wo2], %[r]\n\t"
        "s_nop 1\n\t"
        "v_add_f32_dpp %[p], %[p], %[p] row_ror:8 row_mask:0xf bank_mask:0xf\n\t"
        "s_nop 1\n\t"
        "v_add_f32_dpp %[p], %[p], %[p] row_ror:4 row_mask:0xf bank_mask:0xf\n\t"
        "s_nop 1\n\t"
        "v_add_f32_dpp %[p], %[p], %[p] row_ror:2 row_mask:0xf bank_mask:0xf\n\t"
        "s_nop 1\n\t"
        "v_add_f32_dpp %[p], %[p], %[p] row_ror:1 row_mask:0xf bank_mask:0xf\n\t"
        "s_nop 1\n\t"
        "v_fmac_f32 %[pk], %[p], %[m]"
        : [p]"+v"(p), [pk]"+v"(pk)
        : [r]"v"(r), [wo2]"v"(wo2), [m]"v"(m0));
}

__global__ __launch_bounds__(64, 1) void rnn_kernel(
    const float* __restrict__ x,
    const float* __restrict__ h0,
    const float* __restrict__ W_ih,
    const float* __restrict__ b_ih,
    const float* __restrict__ W_hh,
    const float* __restrict__ b_hh,
    const float* __restrict__ W_out,
    const float* __restrict__ b_out,
    float* __restrict__ out)
{
    const int tid = threadIdx.x;            // 0..63
    // R16: one batch per wave on lanes 0..15; lanes 16..63 exec-masked off.
    // Wave issue cadence is exec-independent -> per-wave stream == R15.
    if (tid >= 16) return;
    const int j   = tid;                    // lane 0..15; j<10 owns dim j
    const int b   = blockIdx.x;             // one batch per block/wave
    const bool jv = (j < HID);
    const int jc  = jv ? j : 0;

    const float CC = 2.88539008177792681472f;   // 2*log2(e)

    const float wih = jv ? W_ih[jc] : 0.0f;
    const float bj  = jv ? (b_ih[jc] + b_hh[jc]) : 0.0f;
    const float wo  = jv ? W_out[jc] : 0.0f;

    float wsh[16];
    float wsum = 0.0f;
#pragma unroll
    for (int N = 0; N < 16; ++N) {
        const int k = (j - N) & 15;
        wsh[N] = (jv && k < HID) ? W_hh[jc * HID + k] : 0.0f;
        wsum += wsh[N];
    }

    // r-form folded constants: a' = C*a with h = 1-2r absorbed.
    const float wih2 = CC * wih;                 // 0 for j>=10
    const float bj2  = CC * (bj + wsum);         // 0 for j>=10
    // Lanes 0..9: -2C*W_hh rows. Lane 10: output row, unscaled (-2*wo), so
    // its accumulated c0 = y - C0. Lanes 11..15: 0.
    float w2[16];
#pragma unroll
    for (int N = 0; N < 16; ++N) {
        if (jv) {
            w2[N] = -2.0f * CC * wsh[N];
        } else if (j == 10) {
            const int k = (10 - N) & 15;
            w2[N] = (k < HID) ? (-2.0f * W_out[k]) : 0.0f;
        } else {
            w2[N] = 0.0f;
        }
    }
    const float wo2 = -2.0f * wo;                // post-loop finisher only
    float c0sum = b_out[0];
#pragma unroll
    for (int k = 0; k < HID; ++k) c0sum += W_out[k];   // C0 = sum(wo) + bo

    // Keep-masks.
    float km[16];
#pragma unroll
    for (int i = 0; i < 16; ++i) km[i] = (j == i) ? 1.0f : 0.0f;

    // r_0 = (1 - h_0)/2 ; idle lanes h0=0 -> r=0.5 (their fixed point).
    float rval = fmaf(-0.5f, jv ? h0[b * HID + jc] : 0.0f, 0.5f);
    float pk = 0.0f;

    const float* xb = x + b;
    float xA[UB], xB[UB];

    issue16(xA, xb);
    wait0_bind(xA);

    for (int t0 = 0; t0 < T_STEPS; t0 += 2 * UB) {
        // ---- half 1: consume xA, prefetch xB ----
        wait1_bind(xA);
        issue16(xB, xb + (size_t)(t0 + UB) * BATCH);
        run16<0>(rval, pk, xA, wih2, bj2, km, w2);
        // Wrap-store: lane j holds y_{t0+j} (j<15); lane 15 holds y_{t0-1}.
        {
            const int tj = t0 + ((j == 15) ? -1 : j);
            if (tj >= 0) out[(size_t)tj * BATCH + b] = pk + c0sum;
        }
        pk = 0.0f;

        // ---- half 2: consume xB, prefetch xA ----
        wait1_bind(xB);
        const float* xsrc = (t0 + 2 * UB < T_STEPS)
                          ? (xb + (size_t)(t0 + 2 * UB) * BATCH) : xb;
        issue16(xA, xsrc);
        run16<0>(rval, pk, xB, wih2, bj2, km, w2);
        {
            const int t1 = t0 + UB;
            const int tj = t1 + ((j == 15) ? -1 : j);
            out[(size_t)tj * BATCH + b] = pk + c0sum;
        }
        pk = 0.0f;
    }

    // Drain the final speculative xA reload while registers are still bound
    // (async-clobber hazard, R6 post-mortem).
    wait0_bind(xA);

    // Final output row t=4095 from final r (R14/R15-proven pattern).
    float p = 0.0f, pk2 = 0.0f;
    finish_reduce(rval, p, pk2, wo2, km[0]);
    if (j == 0) out[(size_t)(T_STEPS - 1) * BATCH + b] = pk2 + c0sum;

    // h_last: h = 1 - 2r
    if (jv) out[(size_t)T_STEPS * BATCH + (size_t)b * HID + j]
                = fmaf(-2.0f, rval, 1.0f);
}

extern "C" void kernel_launch(void* const* d_in, const int* in_sizes, int n_in,
                              void* d_out, int out_size, void* d_ws, size_t ws_size,
                              hipStream_t stream) {
    const float* x     = (const float*)d_in[0];
    const float* h0    = (const float*)d_in[1];
    const float* W_ih  = (const float*)d_in[2];
    const float* b_ih  = (const float*)d_in[3];
    const float* W_hh  = (const float*)d_in[4];
    const float* b_hh  = (const float*)d_in[5];
    const float* W_out = (const float*)d_in[6];
    const float* b_out = (const float*)d_in[7];

    rnn_kernel<<<BATCH, 64, 0, stream>>>(
        x, h0, W_ih, b_ih, W_hh, b_hh, W_out, b_out, (float*)d_out);
}

// Round 9
// 329.165 us; speedup vs baseline: 1.4863x; 1.4863x over previous
//
#include <hip/hip_runtime.h>

#define T_STEPS 4096
#define BATCH   2048
#define HID     10
#define UB      16   // steps per buffer; outer loop advances 2*UB (ping-pong)

// ---- R7/R8-proven load skeleton ------------------------------------------
__device__ __forceinline__ void issue16(float (&xr)[UB], const float* base) {
#pragma unroll
    for (int u = 0; u < UB; ++u)
        asm volatile("global_load_dword %0, %1, off"
                     : "=v"(xr[u]) : "v"(base + (size_t)u * BATCH) : "memory");
}
#define BIND16(a) "+v"(a[0]),"+v"(a[1]),"+v"(a[2]),"+v"(a[3]),"+v"(a[4]), \
    "+v"(a[5]),"+v"(a[6]),"+v"(a[7]),"+v"(a[8]),"+v"(a[9]),"+v"(a[10]),   \
    "+v"(a[11]),"+v"(a[12]),"+v"(a[13]),"+v"(a[14]),"+v"(a[15])
__device__ __forceinline__ void wait1_bind(float (&xr)[UB]) {
    asm volatile("s_waitcnt vmcnt(1)" : BIND16(xr) :: "memory");
}
__device__ __forceinline__ void wait0_bind(float (&xr)[UB]) {
    asm volatile("s_waitcnt vmcnt(0)" : BIND16(xr) :: "memory");
}

// ---- R17: 32-lane split step, permlane32_swap combine ---------------------
// Cost model (fit R8-R16): plain VALU~2cyc, DPP~4, trans~16 pipe-occupancy;
// wall = per-wave demand + ~20 overhead; 1 wave/SIMD optimal (R16).
// Split: batch on 32 lanes. Even half (lanes 0-31, rows 0,1) holds r
// identity, computes eff rotations 0-7 (+seed). Odd half (lanes 32-63,
// rows 2,3) holds rho[j]=r[(j+8)&15], same ror:0-7 -> eff rotations 8-15
// (per-lane weights; R14-proven algebra). Exchange partials across the
// 32-boundary with v_permlane32_swap_b32 (pure VALU, no waitcnt):
//   t = P; swap(P,t)  [P.hi <-> t.lo]  ->  c = P + t = full sum, all lanes.
// Odd-half pre-rotation maintained on the pre-rcp value via masked
// v_mov_b32_dpp ror:8 row_mask:0xc (rotation commutes with per-lane rcp,
// -8 == +8 mod 16; R14-proven). Output row rides on row-local lane 10
// (both halves end with the full row-10 sum), pk extraction as R15.
// Demand: 2+2+7*4+2+4+2+16+4+2+4+16 = 84 vs R15's 104.
#define STEP_HEAD \
    "v_fma_f32 %[P], %[wih2], %[x], %[bj2]\n\t"                                   /* 1 seed (0 on odd half) */ \
    "v_fmac_f32 %[P], %[r], %[w0]\n\t"                                            /* 2 plain r, dist3 from rcp */ \
    "v_fmac_f32_dpp %[P], %[r], %[w1] row_ror:1 row_mask:0xf bank_mask:0xf\n\t"   /* 3 DPP r, dist4 */ \
    "v_fmac_f32_dpp %[P], %[r], %[w2] row_ror:2 row_mask:0xf bank_mask:0xf\n\t"   /* 4 */ \
    "v_fmac_f32_dpp %[P], %[r], %[w3] row_ror:3 row_mask:0xf bank_mask:0xf\n\t"   /* 5 */ \
    "v_fmac_f32_dpp %[P], %[r], %[w4] row_ror:4 row_mask:0xf bank_mask:0xf\n\t"   /* 6 */ \
    "v_fmac_f32_dpp %[P], %[r], %[w5] row_ror:5 row_mask:0xf bank_mask:0xf\n\t"   /* 7 */ \
    "v_fmac_f32_dpp %[P], %[r], %[w6] row_ror:6 row_mask:0xf bank_mask:0xf\n\t"   /* 8 */ \
    "v_fmac_f32_dpp %[P], %[r], %[w7] row_ror:7 row_mask:0xf bank_mask:0xf\n\t"   /* 9 */ \
    "v_mov_b32 %[t], %[P]\n\t"                                                    /* 10 plain read dist1 */ \
    "s_nop 0\n\t"                                                                 /* 11 permlane-src margin */ \
    "v_permlane32_swap_b32 %[P], %[t]\n\t"                                        /* 12 P.hi <-> t.lo */ \
    "s_nop 0\n\t"                                                                 /* 13 permlane-dst margin */ \
    "v_add_f32 %[c], %[P], %[t]\n\t"                                              /* 14 full sum, all lanes */ \
    "v_exp_f32 %[ex], %[c]\n\t"                                                   /* 15 c dist1 (proven) */ \
    "s_nop 0\n\t"                                                                 /* 16 */

#define STEP_TAIL \
    "v_add_f32 %[ex], 1.0, %[ex]\n\t"                                             /* 18 ex dist3 (proven >=2+nop) */ \
    "s_nop 1\n\t"                                                                 /* 19-20 DPP-read spacing */ \
    "v_mov_b32_dpp %[ex], %[ex] row_ror:8 row_mask:0xc bank_mask:0xf\n\t"         /* 21 odd rows: pre-rotate by 8 */ \
    "s_nop 0\n\t"                                                                 /* 22 */ \
    "v_rcp_f32 %[r], %[ex]\n\t"                                                   /* 23 ex dist2 w/nop */ \
    "s_nop 0"                                                                     /* 24 rcp->next r-read dist3 */

// pk extraction (slot 17, c dist3 incl nop — R15-proven spacing):
// lane (U-1)&15 of each row <- row-local lane 10's c via row_ror:(U+5)&15.
#define PKDPP(N) "v_fmac_f32_dpp %[pk], %[c], %[m] row_ror:" #N " row_mask:0xf bank_mask:0xf\n\t"
#define PKPLAIN  "v_fmac_f32 %[pk], %[c], %[m]\n\t"

#define DEF_STEP(SUF, PKLINE_) \
__device__ __forceinline__ void step_##SUF(float& r, float& pk, float x, \
        float wih2, float bj2, float m, const float (&w)[8]) { \
    float P, t, c, ex; \
    asm volatile( STEP_HEAD PKLINE_ STEP_TAIL \
        : [P]"=&v"(P), [t]"=&v"(t), [c]"=&v"(c), [ex]"=&v"(ex), \
          [r]"+v"(r), [pk]"+v"(pk) \
        : [x]"v"(x), [wih2]"v"(wih2), [bj2]"v"(bj2), [m]"v"(m), \
          [w0]"v"(w[0]), [w1]"v"(w[1]), [w2]"v"(w[2]), [w3]"v"(w[3]), \
          [w4]"v"(w[4]), [w5]"v"(w[5]), [w6]"v"(w[6]), [w7]"v"(w[7])); \
}

DEF_STEP(r0,  PKPLAIN)
DEF_STEP(r1,  PKDPP(1))
DEF_STEP(r2,  PKDPP(2))
DEF_STEP(r3,  PKDPP(3))
DEF_STEP(r4,  PKDPP(4))
DEF_STEP(r5,  PKDPP(5))
DEF_STEP(r6,  PKDPP(6))
DEF_STEP(r7,  PKDPP(7))
DEF_STEP(r8,  PKDPP(8))
DEF_STEP(r9,  PKDPP(9))
DEF_STEP(r10, PKDPP(10))
DEF_STEP(r11, PKDPP(11))
DEF_STEP(r12, PKDPP(12))
DEF_STEP(r13, PKDPP(13))
DEF_STEP(r14, PKDPP(14))
DEF_STEP(r15, PKDPP(15))

// Dispatcher: step U extracts out-row t0+U-1 to lane (U-1)&15 via
// ROT=(U+5)&15 (R10/R15-proven). U=0 wraps: mask km[15] -> lane 15 carries
// y_{t0-1}. No per-16 finisher.
template<int U>
__device__ __forceinline__ void step_u(float& r, float& pk, float x,
                                       float wih2, float bj2,
                                       const float (&km)[16],
                                       const float (&w)[8]) {
    constexpr int ROT = (U + 5) & 15;
    const float m = km[(U + 15) & 15];
    if constexpr (ROT == 0)       step_r0 (r, pk, x, wih2, bj2, m, w);
    else if constexpr (ROT == 1)  step_r1 (r, pk, x, wih2, bj2, m, w);
    else if constexpr (ROT == 2)  step_r2 (r, pk, x, wih2, bj2, m, w);
    else if constexpr (ROT == 3)  step_r3 (r, pk, x, wih2, bj2, m, w);
    else if constexpr (ROT == 4)  step_r4 (r, pk, x, wih2, bj2, m, w);
    else if constexpr (ROT == 5)  step_r5 (r, pk, x, wih2, bj2, m, w);
    else if constexpr (ROT == 6)  step_r6 (r, pk, x, wih2, bj2, m, w);
    else if constexpr (ROT == 7)  step_r7 (r, pk, x, wih2, bj2, m, w);
    else if constexpr (ROT == 8)  step_r8 (r, pk, x, wih2, bj2, m, w);
    else if constexpr (ROT == 9)  step_r9 (r, pk, x, wih2, bj2, m, w);
    else if constexpr (ROT == 10) step_r10(r, pk, x, wih2, bj2, m, w);
    else if constexpr (ROT == 11) step_r11(r, pk, x, wih2, bj2, m, w);
    else if constexpr (ROT == 12) step_r12(r, pk, x, wih2, bj2, m, w);
    else if constexpr (ROT == 13) step_r13(r, pk, x, wih2, bj2, m, w);
    else if constexpr (ROT == 14) step_r14(r, pk, x, wih2, bj2, m, w);
    else                          step_r15(r, pk, x, wih2, bj2, m, w);
}

template<int U>
__device__ __forceinline__ void run16(float& r, float& pk, const float (&xr)[UB],
                                      float wih2, float bj2,
                                      const float (&km)[16],
                                      const float (&w)[8]) {
    if constexpr (U < UB) {
        step_u<U>(r, pk, xr[U], wih2, bj2, km, w);
        run16<U + 1>(r, pk, xr, wih2, bj2, km, w);
    }
}

// Post-loop finisher (R8-proven): per-16-row butterfly; even rows hold
// identity r, wo2/m0 are even-gated so odd rows produce 0.
__device__ __forceinline__ void finish_reduce(float r, float& p, float& pk,
                                              float wo2, float m0) {
    asm volatile(
        "v_mul_f32 %[p], %[wo2], %[r]\n\t"
        "s_nop 1\n\t"
        "v_add_f32_dpp %[p], %[p], %[p] row_ror:8 row_mask:0xf bank_mask:0xf\n\t"
        "s_nop 1\n\t"
        "v_add_f32_dpp %[p], %[p], %[p] row_ror:4 row_mask:0xf bank_mask:0xf\n\t"
        "s_nop 1\n\t"
        "v_add_f32_dpp %[p], %[p], %[p] row_ror:2 row_mask:0xf bank_mask:0xf\n\t"
        "s_nop 1\n\t"
        "v_add_f32_dpp %[p], %[p], %[p] row_ror:1 row_mask:0xf bank_mask:0xf\n\t"
        "s_nop 1\n\t"
        "v_fmac_f32 %[pk], %[p], %[m]"
        : [p]"+v"(p), [pk]"+v"(pk)
        : [r]"v"(r), [wo2]"v"(wo2), [m]"v"(m0));
}

__global__ __launch_bounds__(64, 1) void rnn_kernel(
    const float* __restrict__ x,
    const float* __restrict__ h0,
    const float* __restrict__ W_ih,
    const float* __restrict__ b_ih,
    const float* __restrict__ W_hh,
    const float* __restrict__ b_hh,
    const float* __restrict__ W_out,
    const float* __restrict__ b_out,
    float* __restrict__ out)
{
    const int tid  = threadIdx.x;            // 0..63
    const int j    = tid & 15;               // lane-in-row
    const int bsel = (tid >> 4) & 1;         // batch select within wave
    const int half = tid >> 5;               // 0 = even/identity, 1 = odd/pre-rot8
    const int b    = (blockIdx.x << 1) + bsel;
    // Layout: rows 0,1 = (b0,b1) even halves; rows 2,3 = (b0,b1) odd halves.
    // permlane32_swap pairs lane i <-> i+32 = same batch, other half.
    const bool evh = (half == 0);

    const float CC = 2.88539008177792681472f;   // 2*log2(e)

    // 8 rotation weights per lane: ror:N delivers rho[(j-N)&15]; with the
    // half's pre-rotation, source k = (j + 8*half - N)&15, target row j.
    float w[8];
#pragma unroll
    for (int N = 0; N < 8; ++N) {
        const int k = (j + 8 * half - N) & 15;
        float val = 0.0f;
        if (j < HID && k < HID)        val = -2.0f * CC * W_hh[j * HID + k];
        else if (j == 10 && k < HID)   val = -2.0f * W_out[k];   // output row
        w[N] = val;
    }
    // Bias fold, even half only (counted once per row).
    float wsum = 0.0f;
    if (j < HID) {
#pragma unroll
        for (int k = 0; k < HID; ++k) wsum += W_hh[j * HID + k];
    }
    const float wih2 = (evh && j < HID) ? CC * W_ih[j] : 0.0f;
    const float bj2  = (evh && j < HID) ? CC * (b_ih[j] + b_hh[j] + wsum) : 0.0f;
    const float wo2  = (evh && j < HID) ? (-2.0f * W_out[j]) : 0.0f;  // finisher
    float c0sum = b_out[0];
#pragma unroll
    for (int k = 0; k < HID; ++k) c0sum += W_out[k];   // C0 = sum(wo) + bo

    // Keep-masks (even half only stores).
    float km[16];
#pragma unroll
    for (int i = 0; i < 16; ++i) km[i] = (evh && j == i) ? 1.0f : 0.0f;

    // r init: even lanes r[j]; odd lanes rho[j]=r[(j+8)&15]. Invalid -> 0.5.
    const int k0 = (j + 8 * half) & 15;
    float rval = (k0 < HID) ? fmaf(-0.5f, h0[b * HID + k0], 0.5f) : 0.5f;
    float pk = 0.0f;

    const float* xb = x + b;
    float xA[UB], xB[UB];

    issue16(xA, xb);
    wait0_bind(xA);

    for (int t0 = 0; t0 < T_STEPS; t0 += 2 * UB) {
        // ---- half 1: consume xA, prefetch xB ----
        wait1_bind(xA);
        issue16(xB, xb + (size_t)(t0 + UB) * BATCH);
        run16<0>(rval, pk, xA, wih2, bj2, km, w);
        // Wrap-store (even half): lane j holds y_{t0+j} (j<15); lane 15
        // holds y_{t0-1}.
        if (tid < 32) {
            const int tj = t0 + ((j == 15) ? -1 : j);
            if (tj >= 0) out[(size_t)tj * BATCH + b] = pk + c0sum;
        }
        pk = 0.0f;

        // ---- half 2: consume xB, prefetch xA ----
        wait1_bind(xB);
        const float* xsrc = (t0 + 2 * UB < T_STEPS)
                          ? (xb + (size_t)(t0 + 2 * UB) * BATCH) : xb;
        issue16(xA, xsrc);
        run16<0>(rval, pk, xB, wih2, bj2, km, w);
        if (tid < 32) {
            const int t1 = t0 + UB;
            const int tj = t1 + ((j == 15) ? -1 : j);
            out[(size_t)tj * BATCH + b] = pk + c0sum;
        }
        pk = 0.0f;
    }

    // Drain the final speculative xA reload while registers are still bound
    // (async-clobber hazard, R6 post-mortem).
    wait0_bind(xA);

    // Final output row t=4095 from final r (even rows hold identity r).
    float p = 0.0f, pk2 = 0.0f;
    finish_reduce(rval, p, pk2, wo2, km[0]);
    if (tid < 32 && j == 0)
        out[(size_t)(T_STEPS - 1) * BATCH + b] = pk2 + c0sum;

    // h_last: h = 1 - 2r (even half, identity layout).
    if (evh && j < HID)
        out[(size_t)T_STEPS * BATCH + (size_t)b * HID + j] = fmaf(-2.0f, rval, 1.0f);
}

extern "C" void kernel_launch(void* const* d_in, const int* in_sizes, int n_in,
                              void* d_out, int out_size, void* d_ws, size_t ws_size,
                              hipStream_t stream) {
    const float* x     = (const float*)d_in[0];
    const float* h0    = (const float*)d_in[1];
    const float* W_ih  = (const float*)d_in[2];
    const float* b_ih  = (const float*)d_in[3];
    const float* W_hh  = (const float*)d_in[4];
    const float* b_hh  = (const float*)d_in[5];
    const float* W_out = (const float*)d_in[6];
    const float* b_out = (const float*)d_in[7];

    rnn_kernel<<<BATCH / 2, 64, 0, stream>>>(
        x, h0, W_ih, b_ih, W_hh, b_hh, W_out, b_out, (float*)d_out);
}